// Round 1
// baseline (373.433 us; speedup 1.0000x reference)
//
#include <hip/hip_runtime.h>
#include <math.h>

#define Bn 16
#define Tn 32
#define Wn 128
#define Dn 1024

// ---------------------------------------------------------------------------
// Workspace layout (floats):
//   qwp[2][B*D]  @ 0        : partial q_w (2 i-slices)
//   qtp[2][B*D]  @ 32768    : partial q_t
//   cw [B*T*D]   @ 65536    : word-level context per turn
//   ts [B*T]     @ 589824   : turn scores
// total ~2.26 MiB
// ---------------------------------------------------------------------------

// Kernel 1: q = source @ W  for both matrices, i-sliced into 2 partials.
// grid = 64 (mat[2] x chunk[16] x islice[2]), block = 256.
// Thread (lane&15 -> col4 group, (lane>>4)+4*wv -> b). W loads are float4,
// 16 distinct float4 per wave (256B, merged); source via LDS broadcast,
// stride 520 => banks 8*b apart => conflict-free across the 4 b's per wave.
__global__ __launch_bounds__(256) void qproj_kernel(
    const float* __restrict__ src, const float* __restrict__ Ww,
    const float* __restrict__ Wt, float* __restrict__ qwp, float* __restrict__ qtp)
{
    __shared__ float s_lds[16 * 520];
    const int tid = threadIdx.x;
    const int mat = blockIdx.x >> 5;
    const int chunk = (blockIdx.x >> 1) & 15;
    const int isl = blockIdx.x & 1;

    // stage source slice: 16 b x 512 i
    for (int k = 0; k < 32; ++k) {
        int idx = k * 256 + tid;
        int bb = idx >> 9, ii = idx & 511;
        s_lds[bb * 520 + ii] = src[bb * 1024 + isl * 512 + ii];
    }
    __syncthreads();

    const int lane = tid & 63, wv = tid >> 6;
    const int col4 = chunk * 16 + (lane & 15);
    const int b = (lane >> 4) + 4 * wv;
    const float4* W4 = (const float4*)(mat ? Wt : Ww);
    const float* sb = s_lds + b * 520;

    float4 acc = make_float4(0.f, 0.f, 0.f, 0.f);
    #pragma unroll 8
    for (int ii = 0; ii < 512; ++ii) {
        int i = isl * 512 + ii;
        float4 w4 = W4[i * 256 + col4];
        float s = sb[ii];
        acc.x = fmaf(s, w4.x, acc.x);
        acc.y = fmaf(s, w4.y, acc.y);
        acc.z = fmaf(s, w4.z, acc.z);
        acc.w = fmaf(s, w4.w, acc.w);
    }
    float* qo = (mat ? qtp : qwp) + isl * (Bn * Dn);
    ((float4*)(qo + b * Dn))[col4] = acc;
}

// Kernel 2: per-(b,t) word-level attention with online softmax, single pass
// over memory_bank. grid = B*T = 512, block = 512 (8 waves).
__global__ __launch_bounds__(512) void word_attn_kernel(
    const float* __restrict__ mem, const float* __restrict__ qwp,
    const float* __restrict__ qtp, const int* __restrict__ lens,
    const int* __restrict__ turns, float* __restrict__ cw, float* __restrict__ ts)
{
    const int bt = blockIdx.x;
    const int b = bt >> 5, t = bt & 31;
    if (t >= turns[b]) return;            // masked turn: never consumed downstream
    const int len = lens[bt];

    const int tid = threadIdx.x, lane = tid & 63, wv = tid >> 6;
    const float* rowb = mem + (size_t)bt * (Wn * Dn);

    // q_w fragment: lane holds d = c*256 + lane*4 + j  (c in 0..3, j in 0..3)
    const float4* qa = (const float4*)(qwp + b * Dn);
    const float4* qb = (const float4*)(qwp + Bn * Dn + b * Dn);
    float4 q[4];
    #pragma unroll
    for (int c = 0; c < 4; ++c) {
        float4 a = qa[c * 64 + lane], bb = qb[c * 64 + lane];
        q[c] = make_float4(a.x + bb.x, a.y + bb.y, a.z + bb.z, a.w + bb.w);
    }

    float m = -INFINITY, l = 0.f;
    float4 acc[4];
    #pragma unroll
    for (int c = 0; c < 4; ++c) acc[c] = make_float4(0.f, 0.f, 0.f, 0.f);

    for (int w = wv; w < len; w += 8) {
        const float4* r4 = (const float4*)(rowb + (size_t)w * Dn);
        float4 x[4];
        #pragma unroll
        for (int c = 0; c < 4; ++c) x[c] = r4[c * 64 + lane];
        float s = 0.f;
        #pragma unroll
        for (int c = 0; c < 4; ++c) {
            s = fmaf(q[c].x, x[c].x, s);
            s = fmaf(q[c].y, x[c].y, s);
            s = fmaf(q[c].z, x[c].z, s);
            s = fmaf(q[c].w, x[c].w, s);
        }
        #pragma unroll
        for (int off = 32; off >= 1; off >>= 1) s += __shfl_xor(s, off, 64);

        float mn = fmaxf(m, s);
        float sc = (m == -INFINITY) ? 0.f : __expf(m - mn);
        float p = __expf(s - mn);
        l = l * sc + p;
        #pragma unroll
        for (int c = 0; c < 4; ++c) {
            acc[c].x = fmaf(acc[c].x, sc, p * x[c].x);
            acc[c].y = fmaf(acc[c].y, sc, p * x[c].y);
            acc[c].z = fmaf(acc[c].z, sc, p * x[c].z);
            acc[c].w = fmaf(acc[c].w, sc, p * x[c].w);
        }
        m = mn;
    }

    // merge the 8 per-wave online-softmax states
    __shared__ float m_s[8], l_s[8], red[8];
    __shared__ float acc_s[8 * 1024];
    if (lane == 0) { m_s[wv] = m; l_s[wv] = l; }
    float4* as4 = (float4*)(acc_s + wv * 1024);
    #pragma unroll
    for (int c = 0; c < 4; ++c) as4[c * 64 + lane] = acc[c];
    __syncthreads();

    float M = -INFINITY;
    #pragma unroll
    for (int v = 0; v < 8; ++v) M = fmaxf(M, m_s[v]);
    float L = 0.f, cx = 0.f, cy = 0.f;
    const float2* a2 = (const float2*)acc_s;
    #pragma unroll
    for (int v = 0; v < 8; ++v) {
        float f = (l_s[v] > 0.f) ? __expf(m_s[v] - M) : 0.f;
        L += f * l_s[v];
        float2 a = a2[v * 512 + tid];
        cx = fmaf(f, a.x, cx);
        cy = fmaf(f, a.y, cy);
    }
    float inv = 1.f / L;                  // L > 0: len >= 1 guarantees a valid row
    cx *= inv; cy *= inv;
    ((float2*)(cw + (size_t)bt * Dn))[tid] = make_float2(cx, cy);

    // turn score: dot(q_t[b], cw[b,t])
    const float2* qta = (const float2*)(qtp + b * Dn);
    const float2* qtb = (const float2*)(qtp + Bn * Dn + b * Dn);
    float2 t0 = qta[tid], t1 = qtb[tid];
    float p = (t0.x + t1.x) * cx + (t0.y + t1.y) * cy;
    #pragma unroll
    for (int off = 32; off >= 1; off >>= 1) p += __shfl_xor(p, off, 64);
    if (lane == 0) red[wv] = p;
    __syncthreads();
    if (tid == 0) {
        float r = 0.f;
        #pragma unroll
        for (int v = 0; v < 8; ++v) r += red[v];
        ts[bt] = r;
    }
}

// Kernel 3: turn-level masked softmax + weighted sum. grid = B, block = 256.
__global__ __launch_bounds__(256) void turn_attn_kernel(
    const float* __restrict__ cw, const float* __restrict__ ts,
    const int* __restrict__ turns, float* __restrict__ out)
{
    const int b = blockIdx.x;
    const int n = turns[b];               // in [1, 32]
    const int tid = threadIdx.x;
    __shared__ float attn[32];
    if (tid < 32) {
        float s = (tid < n) ? ts[b * Tn + tid] : -INFINITY;
        float mm = s;
        #pragma unroll
        for (int off = 16; off >= 1; off >>= 1) mm = fmaxf(mm, __shfl_xor(mm, off, 32));
        float e = (tid < n) ? __expf(s - mm) : 0.f;
        float sum = e;
        #pragma unroll
        for (int off = 16; off >= 1; off >>= 1) sum += __shfl_xor(sum, off, 32);
        attn[tid] = e / sum;
    }
    __syncthreads();
    float4 a = make_float4(0.f, 0.f, 0.f, 0.f);
    for (int tt = 0; tt < n; ++tt) {      // only valid turns -> poisoned cw never read
        float wgt = attn[tt];
        float4 c = ((const float4*)(cw + ((size_t)b * Tn + tt) * Dn))[tid];
        a.x = fmaf(wgt, c.x, a.x);
        a.y = fmaf(wgt, c.y, a.y);
        a.z = fmaf(wgt, c.z, a.z);
        a.w = fmaf(wgt, c.w, a.w);
    }
    ((float4*)(out + b * Dn))[tid] = a;
}

extern "C" void kernel_launch(void* const* d_in, const int* in_sizes, int n_in,
                              void* d_out, int out_size, void* d_ws, size_t ws_size,
                              hipStream_t stream) {
    (void)in_sizes; (void)n_in; (void)out_size; (void)ws_size;
    const float* src   = (const float*)d_in[0];
    const float* mem   = (const float*)d_in[1];
    const int*   lens  = (const int*)d_in[2];
    const int*   turns = (const int*)d_in[3];
    const float* Ww    = (const float*)d_in[4];
    const float* Wt    = (const float*)d_in[5];
    float* ws  = (float*)d_ws;
    float* qwp = ws;                          // 2 * 16384
    float* qtp = ws + 2 * Bn * Dn;            // 2 * 16384
    float* cw  = ws + 4 * Bn * Dn;            // B*T*D
    float* ts  = cw + (size_t)Bn * Tn * Dn;   // B*T
    float* out = (float*)d_out;

    hipLaunchKernelGGL(qproj_kernel, dim3(64), dim3(256), 0, stream,
                       src, Ww, Wt, qwp, qtp);
    hipLaunchKernelGGL(word_attn_kernel, dim3(Bn * Tn), dim3(512), 0, stream,
                       mem, qwp, qtp, lens, turns, cw, ts);
    hipLaunchKernelGGL(turn_attn_kernel, dim3(Bn), dim3(256), 0, stream,
                       cw, ts, turns, out);
}

// Round 2
// 351.825 us; speedup vs baseline: 1.0614x; 1.0614x over previous
//
#include <hip/hip_runtime.h>
#include <math.h>

#define Bn 16
#define Tn 32
#define Wn 128
#define Dn 1024

// ---------------------------------------------------------------------------
// Workspace layout (floats):
//   qwp[8][B*D] @ 0        : partial q_w (8 i-slices)
//   qtp[8][B*D] @ 131072   : partial q_t
//   qw [B*D]    @ 262144   : reduced q_w
//   qt [B*D]    @ 278528   : reduced q_t
//   cw [B*T*D]  @ 294912   : word-level context per turn
//   ts [B*T]    @ 819200   : turn scores
// ---------------------------------------------------------------------------

// Kernel 1: q = source @ W, i-sliced 8 ways for full-chip parallelism.
// grid = 256 (mat[2] x chunk[16] x islice[8]), block = 256. Each block reads
// a 128x64-col slab of W exactly once (32 KiB); W total read = 8 MiB.
__global__ __launch_bounds__(256) void qproj_kernel(
    const float* __restrict__ src, const float* __restrict__ Ww,
    const float* __restrict__ Wt, float* __restrict__ qwp, float* __restrict__ qtp)
{
    __shared__ float s_lds[16 * 132];   // stride 132: banks 4*b apart per quarter-wave
    const int tid = threadIdx.x;
    const int mat = blockIdx.x >> 7;
    const int chunk = (blockIdx.x >> 3) & 15;
    const int isl = blockIdx.x & 7;

    // stage source slice: 16 b x 128 i
    #pragma unroll
    for (int k = 0; k < 8; ++k) {
        int idx = k * 256 + tid;
        int bb = idx >> 7, ii = idx & 127;
        s_lds[bb * 132 + ii] = src[bb * Dn + isl * 128 + ii];
    }
    __syncthreads();

    const int lane = tid & 63, wv = tid >> 6;
    const int col4 = chunk * 16 + (lane & 15);
    const int b = (lane >> 4) + 4 * wv;
    const float4* W4 = (const float4*)(mat ? Wt : Ww);
    const float* sb = s_lds + b * 132;

    float4 acc = make_float4(0.f, 0.f, 0.f, 0.f);
    #pragma unroll 8
    for (int ii = 0; ii < 128; ++ii) {
        float4 w4 = W4[(size_t)(isl * 128 + ii) * 256 + col4];
        float s = sb[ii];
        acc.x = fmaf(s, w4.x, acc.x);
        acc.y = fmaf(s, w4.y, acc.y);
        acc.z = fmaf(s, w4.z, acc.z);
        acc.w = fmaf(s, w4.w, acc.w);
    }
    float* qo = (mat ? qtp : qwp) + isl * (Bn * Dn);
    ((float4*)(qo + b * Dn))[col4] = acc;
}

// Kernel 1b: collapse the 8 i-slices. grid = 32 (16 for qw, 16 for qt), block 256.
__global__ __launch_bounds__(256) void qreduce_kernel(
    const float* __restrict__ qwp, const float* __restrict__ qtp,
    float* __restrict__ qw, float* __restrict__ qt)
{
    const int blk = blockIdx.x;
    const float4* in4 = (const float4*)((blk & 16) ? qtp : qwp);
    float4* out4 = (float4*)((blk & 16) ? qt : qw);
    const int idx = (blk & 15) * 256 + threadIdx.x;   // 0..4095 float4s
    float4 a = make_float4(0.f, 0.f, 0.f, 0.f);
    #pragma unroll
    for (int s = 0; s < 8; ++s) {
        float4 v = in4[s * 4096 + idx];
        a.x += v.x; a.y += v.y; a.z += v.z; a.w += v.w;
    }
    out4[idx] = a;
}

// Kernel 2: per-(b,t) word-level attention, online softmax, single pass over
// memory_bank. grid = B*T = 512, block = 1024 (16 waves) to halve the
// per-block critical path on long turns.
__global__ __launch_bounds__(1024) void word_attn_kernel(
    const float* __restrict__ mem, const float* __restrict__ qw,
    const float* __restrict__ qt, const int* __restrict__ lens,
    const int* __restrict__ turns, float* __restrict__ cw, float* __restrict__ ts)
{
    const int bt = blockIdx.x;
    const int b = bt >> 5, t = bt & 31;
    if (t >= turns[b]) return;            // masked turn: never consumed downstream
    const int len = lens[bt];

    const int tid = threadIdx.x, lane = tid & 63, wv = tid >> 6;   // wv in 0..15
    const float* rowb = mem + (size_t)bt * (Wn * Dn);

    // q fragment: lane holds d = c*256 + lane*4 + j (c in 0..3, j in 0..3)
    const float4* qa = (const float4*)(qw + b * Dn);
    float4 q[4];
    #pragma unroll
    for (int c = 0; c < 4; ++c) q[c] = qa[c * 64 + lane];

    float m = -INFINITY, l = 0.f;
    float4 acc[4];
    #pragma unroll
    for (int c = 0; c < 4; ++c) acc[c] = make_float4(0.f, 0.f, 0.f, 0.f);

    for (int w = wv; w < len; w += 16) {
        const float4* r4 = (const float4*)(rowb + (size_t)w * Dn);
        float4 x[4];
        #pragma unroll
        for (int c = 0; c < 4; ++c) x[c] = r4[c * 64 + lane];
        float s = 0.f;
        #pragma unroll
        for (int c = 0; c < 4; ++c) {
            s = fmaf(q[c].x, x[c].x, s);
            s = fmaf(q[c].y, x[c].y, s);
            s = fmaf(q[c].z, x[c].z, s);
            s = fmaf(q[c].w, x[c].w, s);
        }
        #pragma unroll
        for (int off = 32; off >= 1; off >>= 1) s += __shfl_xor(s, off, 64);

        float mn = fmaxf(m, s);
        float sc = (m == -INFINITY) ? 0.f : __expf(m - mn);
        float p = __expf(s - mn);
        l = l * sc + p;
        #pragma unroll
        for (int c = 0; c < 4; ++c) {
            acc[c].x = fmaf(acc[c].x, sc, p * x[c].x);
            acc[c].y = fmaf(acc[c].y, sc, p * x[c].y);
            acc[c].z = fmaf(acc[c].z, sc, p * x[c].z);
            acc[c].w = fmaf(acc[c].w, sc, p * x[c].w);
        }
        m = mn;
    }

    // merge the 16 per-wave online-softmax states
    __shared__ float m_s[16], l_s[16], red[16];
    __shared__ float acc_s[16 * 1024];
    if (lane == 0) { m_s[wv] = m; l_s[wv] = l; }
    float4* as4 = (float4*)(acc_s + wv * 1024);
    #pragma unroll
    for (int c = 0; c < 4; ++c) as4[c * 64 + lane] = acc[c];
    __syncthreads();

    float M = -INFINITY;
    #pragma unroll
    for (int v = 0; v < 16; ++v) M = fmaxf(M, m_s[v]);
    float L = 0.f, cacc = 0.f;
    #pragma unroll
    for (int v = 0; v < 16; ++v) {
        float f = (l_s[v] > 0.f) ? __expf(m_s[v] - M) : 0.f;
        L += f * l_s[v];
        cacc = fmaf(f, acc_s[v * 1024 + tid], cacc);
    }
    cacc *= 1.f / L;                      // L > 0: len >= 1 guarantees a valid row
    cw[(size_t)bt * Dn + tid] = cacc;

    // turn score: dot(q_t[b], cw[b,t]) across the whole block
    float p = qt[b * Dn + tid] * cacc;
    #pragma unroll
    for (int off = 32; off >= 1; off >>= 1) p += __shfl_xor(p, off, 64);
    if (lane == 0) red[wv] = p;
    __syncthreads();
    if (tid == 0) {
        float r = 0.f;
        #pragma unroll
        for (int v = 0; v < 16; ++v) r += red[v];
        ts[bt] = r;
    }
}

// Kernel 3: turn-level masked softmax + weighted sum. grid = B, block = 256.
__global__ __launch_bounds__(256) void turn_attn_kernel(
    const float* __restrict__ cw, const float* __restrict__ ts,
    const int* __restrict__ turns, float* __restrict__ out)
{
    const int b = blockIdx.x;
    const int n = turns[b];               // in [1, 32]
    const int tid = threadIdx.x;
    __shared__ float attn[32];
    if (tid < 32) {
        float s = (tid < n) ? ts[b * Tn + tid] : -INFINITY;
        float mm = s;
        #pragma unroll
        for (int off = 16; off >= 1; off >>= 1) mm = fmaxf(mm, __shfl_xor(mm, off, 32));
        float e = (tid < n) ? __expf(s - mm) : 0.f;
        float sum = e;
        #pragma unroll
        for (int off = 16; off >= 1; off >>= 1) sum += __shfl_xor(sum, off, 32);
        attn[tid] = e / sum;
    }
    __syncthreads();
    float4 a = make_float4(0.f, 0.f, 0.f, 0.f);
    for (int tt = 0; tt < n; ++tt) {      // only valid turns -> poisoned cw never read
        float wgt = attn[tt];
        float4 c = ((const float4*)(cw + ((size_t)b * Tn + tt) * Dn))[tid];
        a.x = fmaf(wgt, c.x, a.x);
        a.y = fmaf(wgt, c.y, a.y);
        a.z = fmaf(wgt, c.z, a.z);
        a.w = fmaf(wgt, c.w, a.w);
    }
    ((float4*)(out + b * Dn))[tid] = a;
}

extern "C" void kernel_launch(void* const* d_in, const int* in_sizes, int n_in,
                              void* d_out, int out_size, void* d_ws, size_t ws_size,
                              hipStream_t stream) {
    (void)in_sizes; (void)n_in; (void)out_size; (void)ws_size;
    const float* src   = (const float*)d_in[0];
    const float* mem   = (const float*)d_in[1];
    const int*   lens  = (const int*)d_in[2];
    const int*   turns = (const int*)d_in[3];
    const float* Ww    = (const float*)d_in[4];
    const float* Wt    = (const float*)d_in[5];
    float* ws  = (float*)d_ws;
    float* qwp = ws;                              // 8 * 16384
    float* qtp = ws + 8 * Bn * Dn;                // 8 * 16384
    float* qw  = ws + 16 * Bn * Dn;               // 16384
    float* qt  = ws + 17 * Bn * Dn;               // 16384
    float* cw  = ws + 18 * Bn * Dn;               // B*T*D
    float* ts  = cw + (size_t)Bn * Tn * Dn;       // B*T
    float* out = (float*)d_out;

    hipLaunchKernelGGL(qproj_kernel, dim3(256), dim3(256), 0, stream,
                       src, Ww, Wt, qwp, qtp);
    hipLaunchKernelGGL(qreduce_kernel, dim3(32), dim3(256), 0, stream,
                       qwp, qtp, qw, qt);
    hipLaunchKernelGGL(word_attn_kernel, dim3(Bn * Tn), dim3(1024), 0, stream,
                       mem, qw, qt, lens, turns, cw, ts);
    hipLaunchKernelGGL(turn_attn_kernel, dim3(Bn), dim3(256), 0, stream,
                       cw, ts, turns, out);
}